// Round 4
// baseline (272.786 us; speedup 1.0000x reference)
//
#include <hip/hip_runtime.h>
#include <math.h>

// DiffractiveLayer: out[j] = sum_i modes[i]*G[i,j]*dA, G[i,j] = f(a-c, b-d)
// -> 2D complex convolution with a 191x191 tap table.
// Single fused kernel (taps+modes -> grid barrier -> register-blocked conv
// -> arrive-only barrier -> reduce), counters/partials in d_ws.
//
// Timed-iteration budget is dominated by the harness's 268 MB d_ws poison
// fill (~39.5 us at 85% HBM peak); this round minimizes our dispatch count
// (2: tiny memset + fused kernel) and removes atomics/memset-out.

#define NN 96
#define M (NN*NN)
#define GH 191           // 2N-1 tap rows/cols
#define GWG 192          // global tap row stride (float2)
#define GW2 200          // LDS tap row stride (float2), slack for ring overrun
#define MW2 104          // LDS modes row stride (float2), de-banked
#define NBLK (NN*12)     // 1152 blocks

__device__ float2 g_G[GH * GWG];    // tap table, dA folded in
__device__ float2 g_modes[M];       // exp(j*w)*x

// __launch_bounds__(192,4): 3 waves/block, >=4 waves/EU -> VGPR<=128 ->
// >=5 blocks/CU (LDS 25.7KB -> 6) -> capacity 1280 >= 1152: barrier-1 safe.
__global__ __launch_bounds__(192, 4) void fused_kernel(
    const float* __restrict__ x, const float* __restrict__ w,
    const float* __restrict__ xc, const float* __restrict__ yc,
    float* __restrict__ out, int interleaved,
    int* __restrict__ cnt, float2* __restrict__ part) {

  const int c     = blockIdx.x;
  const int chunk = blockIdx.y;
  const int a0    = chunk * 8;
  const int t     = threadIdx.x;
  const int gid   = (chunk * NN + c) * 192 + t;

  // ---------------- phase 1: taps + modes ----------------
  const double DZ = 1e-5, LAMBDA = 1.55e-6;
  const double TWO_PI     = 6.283185307179586476925;
  const double INV_TWO_PI = 0.15915494309189533577;
  const double K  = TWO_PI / LAMBDA;
  const double DA = LAMBDA * LAMBDA;          // pitch == lambda

  if (gid < GH * GH) {
    int u = gid / GH - (NN - 1);
    int v = gid % GH - (NN - 1);
    // fp32-rounded input coords match the reference's systematic rounding
    double dx = (double)xc[u < 0 ? -u : u] - (double)xc[0];
    double dy = (double)yc[v < 0 ? -v : v] - (double)yc[0];
    double r2 = dx * dx + dy * dy + DZ * DZ;
    double r  = sqrt(r2);
    double invr2 = 1.0 / r2;
    double amp = DZ * DA * invr2;               // dz/r^2 * dA
    double A = amp * INV_TWO_PI * (r * invr2);  // amp/(2*pi*r)
    double B = amp / LAMBDA;
    double ph = K * r;                          // up to ~843 rad
    double nred = rint(ph * INV_TWO_PI);
    float red = (float)fma(-nred, TWO_PI, ph);  // |red| <= pi, err ~1e-13
    float s, cs;
    __sincosf(red, &s, &cs);
    // (A - jB)(cs + js) = (A cs + B s) + j(A s - B cs)
    g_G[(u + NN - 1) * GWG + (v + NN - 1)] =
        make_float2((float)(A * cs + B * s), (float)(A * s - B * cs));
  } else if (gid < GH * GH + M) {
    int i = gid - GH * GH;
    float s, cs;
    sincosf(w[i], &s, &cs);
    float xv = x[i];
    g_modes[i] = make_float2(cs * xv, s * xv);
  }

  // ---------------- grid barrier 1 (all-wait) ----------------
  __threadfence();
  __syncthreads();
  if (t == 0) {
    __hip_atomic_fetch_add(cnt, 1, __ATOMIC_RELEASE, __HIP_MEMORY_SCOPE_AGENT);
    while (__hip_atomic_load(cnt, __ATOMIC_ACQUIRE, __HIP_MEMORY_SCOPE_AGENT) < NBLK)
      __builtin_amdgcn_s_sleep(2);
  }
  __syncthreads();

  // ---------------- phase 2: register-blocked conv ----------------
  __shared__ float2 s_modes[8 * MW2];      // 8 rows x 96 (stride 104)
  __shared__ float2 s_G[8 * GW2 + 8];      // 8 rows x 192 (stride 200) + slack
  __shared__ float2 s_red[8 * NN];

  // stage modes: 8 rows x 48 float4, 2 per thread
  #pragma unroll
  for (int k = 0; k < 2; ++k) {
    int idx = k * 192 + t;              // 0..383
    int row = idx / 48, col = idx % 48;
    const float4* src = (const float4*)(g_modes + (a0 + row) * NN);
    ((float4*)(s_modes + row * MW2))[col] = src[col];
  }
  // stage taps: 8 rows x 96 float4, 4 per thread
  #pragma unroll
  for (int k = 0; k < 4; ++k) {
    int idx = k * 192 + t;              // 0..767
    int row = idx / 96, col = idx % 96;
    const float4* src = (const float4*)(g_G + (a0 + row - c + (NN - 1)) * GWG);
    ((float4*)(s_G + row * GW2))[col] = src[col];
  }
  __syncthreads();

  int q = t % 24;
  int h = t / 24;
  int base = 92 - 4 * q;                // even, >= 0
  const float4* Grow = (const float4*)(s_G + h * GW2);
  const float4* Mrow = (const float4*)(s_modes + h * MW2);
  int gb = base >> 1;

  float4 g0 = Grow[gb];
  float4 g1 = Grow[gb + 1];
  float4 g2 = Grow[gb + 2];
  float2 a0c = {0.f, 0.f}, a1c = {0.f, 0.f}, a2c = {0.f, 0.f}, a3c = {0.f, 0.f};

#define CFMA(acc, mr, mi, gr, gi)                 \
  acc.x = fmaf(mr, gr, acc.x);                    \
  acc.x = fmaf(-(mi), gi, acc.x);                 \
  acc.y = fmaf(mr, gi, acc.y);                    \
  acc.y = fmaf(mi, gr, acc.y)

  for (int b = 0; b < NN; b += 2) {
    float4 mm = Mrow[b >> 1];   // m[b]=(x,y)  m[b+1]=(z,w)
    CFMA(a0c, mm.x, mm.y, g1.z, g1.w);
    CFMA(a0c, mm.z, mm.w, g2.x, g2.y);
    CFMA(a1c, mm.x, mm.y, g1.x, g1.y);
    CFMA(a1c, mm.z, mm.w, g1.z, g1.w);
    CFMA(a2c, mm.x, mm.y, g0.z, g0.w);
    CFMA(a2c, mm.z, mm.w, g1.x, g1.y);
    CFMA(a3c, mm.x, mm.y, g0.x, g0.y);
    CFMA(a3c, mm.z, mm.w, g0.z, g0.w);
    g0 = g1;
    g1 = g2;
    g2 = Grow[gb + 3 + (b >> 1)];   // slack covers final overrun
  }
#undef CFMA

  int dbase = 4 * q;
  s_red[h * NN + dbase + 0] = a0c;
  s_red[h * NN + dbase + 1] = a1c;
  s_red[h * NN + dbase + 2] = a2c;
  s_red[h * NN + dbase + 3] = a3c;
  __syncthreads();

  if (t < NN) {
    float re = 0.f, im = 0.f;
    #pragma unroll
    for (int hh = 0; hh < 8; ++hh) {
      re += s_red[hh * NN + t].x;
      im += s_red[hh * NN + t].y;
    }
    part[chunk * M + c * NN + t] = make_float2(re, im);  // coalesced
  }

  // ---------------- barrier 2 (arrive-only for chunk != 0) ----------------
  __threadfence();
  __syncthreads();
  if (t == 0)
    __hip_atomic_fetch_add(cnt + 1, 1, __ATOMIC_RELEASE, __HIP_MEMORY_SCOPE_AGENT);
  if (chunk != 0) return;

  if (t == 0) {
    while (__hip_atomic_load(cnt + 1, __ATOMIC_ACQUIRE, __HIP_MEMORY_SCOPE_AGENT) < NBLK)
      __builtin_amdgcn_s_sleep(2);
  }
  __syncthreads();

  if (t < NN) {
    float re = 0.f, im = 0.f;
    #pragma unroll
    for (int k = 0; k < 12; ++k) {
      float2 p = part[k * M + c * NN + t];
      re += p.x;
      im += p.y;
    }
    int j = c * NN + t;
    if (interleaved) {
      out[2 * j]     = re;
      out[2 * j + 1] = im;
    } else {
      out[j] = re;
    }
  }
}

extern "C" void kernel_launch(void* const* d_in, const int* in_sizes, int n_in,
                              void* d_out, int out_size, void* d_ws, size_t ws_size,
                              hipStream_t stream) {
  const float* x  = (const float*)d_in[0];
  const float* w  = (const float*)d_in[1];
  const float* xc = (const float*)d_in[2];
  const float* yc = (const float*)d_in[3];
  float* out = (float*)d_out;

  int*    cnt  = (int*)d_ws;
  float2* part = (float2*)((char*)d_ws + 256);

  hipMemsetAsync(d_ws, 0, 256, stream);   // zero both barrier counters

  int interleaved = (out_size >= 2 * M) ? 1 : 0;
  fused_kernel<<<dim3(NN, 12), 192, 0, stream>>>(x, w, xc, yc, out,
                                                 interleaved, cnt, part);
}

// Round 5
// 73.886 us; speedup vs baseline: 3.6920x; 3.6920x over previous
//
#include <hip/hip_runtime.h>
#include <math.h>

// DiffractiveLayer: out[j] = sum_i modes[i]*G[i,j]*dA, G[i,j] = f(a-c, b-d)
// -> 2D complex convolution with a 191x191 tap table.
//
// Structure (R4): TWO dispatches only.
//   1. precompute: taps (fp64 geometry + arg-reduced hw sincos) + modes
//      + zero d_out (replaces a separate memset dispatch).
//   2. conv: register-blocked direct convolution out of LDS, 12-way
//      atomicAdd accumulation into d_out.
// R3's single-kernel + device-scope spin-barrier variant measured 241 us:
// cross-XCD coherence storms make grid barriers ~100x the cost of the
// launch gaps they save. Never again on this chip.
//
// Timed-iteration floor: harness poisons 268 MB of d_ws every iteration
// (~39.5 us at ~85% HBM peak) + graph replay overhead. Our dispatches are
// ~10 us combined.

#define NN 96
#define M (NN*NN)
#define GH 191           // 2N-1 tap rows/cols
#define GWG 192          // global tap row stride (float2)
#define GW2 200          // LDS tap row stride (float2), slack for ring overrun
#define MW2 104          // LDS modes row stride (float2), de-banked

__device__ float2 g_G[GH * GWG];    // tap table, dA folded in
__device__ float2 g_modes[M];       // exp(j*w)*x

__global__ __launch_bounds__(256) void precompute_kernel(
    const float* __restrict__ x, const float* __restrict__ w,
    const float* __restrict__ xc, const float* __restrict__ yc,
    float* __restrict__ out, int out_floats) {
  const double DZ = 1e-5, LAMBDA = 1.55e-6;
  const double TWO_PI     = 6.283185307179586476925;
  const double INV_TWO_PI = 0.15915494309189533577;
  const double K  = TWO_PI / LAMBDA;
  const double DA = LAMBDA * LAMBDA;          // pitch == lambda

  int idx = blockIdx.x * 256 + threadIdx.x;

  if (idx < out_floats) out[idx] = 0.f;       // fused d_out zeroing

  if (idx < GH * GH) {
    int u = idx / GH - (NN - 1);
    int v = idx % GH - (NN - 1);
    // fp32-rounded input coords match the reference's systematic rounding
    double dx = (double)xc[u < 0 ? -u : u] - (double)xc[0];
    double dy = (double)yc[v < 0 ? -v : v] - (double)yc[0];
    double r2 = dx * dx + dy * dy + DZ * DZ;
    double r  = sqrt(r2);
    double invr2 = 1.0 / r2;
    double amp = DZ * DA * invr2;               // dz/r^2 * dA
    double A = amp * INV_TWO_PI * (r * invr2);  // amp/(2*pi*r)
    double B = amp / LAMBDA;
    double ph = K * r;                          // up to ~843 rad
    double nred = rint(ph * INV_TWO_PI);
    float red = (float)fma(-nred, TWO_PI, ph);  // |red| <= pi, err ~1e-13
    float s, cs;
    __sincosf(red, &s, &cs);
    // (A - jB)(cs + js) = (A cs + B s) + j(A s - B cs)
    g_G[(u + NN - 1) * GWG + (v + NN - 1)] =
        make_float2((float)(A * cs + B * s), (float)(A * s - B * cs));
  } else if (idx < GH * GH + M) {
    int i = idx - GH * GH;
    float s, cs;
    sincosf(w[i], &s, &cs);
    float xv = x[i];
    g_modes[i] = make_float2(cs * xv, s * xv);
  }
}

// grid: (96 output rows c, 12 source-row chunks of 8), block 192.
// Thread t: q = t%24 -> outputs d = 4q..4q+3;  h = t/24 -> source row a0+h.
// Register ring of 3 float4 (6 taps) -> 1 new b128 tap read per 2 b-steps.
__global__ __launch_bounds__(192) void conv_kernel(float* __restrict__ out,
                                                   int interleaved) {
  int c  = blockIdx.x;
  int a0 = blockIdx.y * 8;
  int t  = threadIdx.x;

  __shared__ float2 s_modes[8 * MW2];      // 8 rows x 96 (stride 104)
  __shared__ float2 s_G[8 * GW2 + 8];      // 8 rows x 192 (stride 200) + slack
  __shared__ float2 s_red[8 * NN];

  // stage modes: 8 rows x 48 float4, 2 per thread
  #pragma unroll
  for (int k = 0; k < 2; ++k) {
    int idx = k * 192 + t;              // 0..383
    int row = idx / 48, col = idx % 48;
    const float4* src = (const float4*)(g_modes + (a0 + row) * NN);
    ((float4*)(s_modes + row * MW2))[col] = src[col];
  }
  // stage taps: 8 rows x 96 float4, 4 per thread
  #pragma unroll
  for (int k = 0; k < 4; ++k) {
    int idx = k * 192 + t;              // 0..767
    int row = idx / 96, col = idx % 96;
    const float4* src = (const float4*)(g_G + (a0 + row - c + (NN - 1)) * GWG);
    ((float4*)(s_G + row * GW2))[col] = src[col];
  }
  __syncthreads();

  int q = t % 24;
  int h = t / 24;
  int base = 92 - 4 * q;                // even, >= 0
  const float4* Grow = (const float4*)(s_G + h * GW2);
  const float4* Mrow = (const float4*)(s_modes + h * MW2);
  int gb = base >> 1;

  float4 g0 = Grow[gb];
  float4 g1 = Grow[gb + 1];
  float4 g2 = Grow[gb + 2];
  float2 a0c = {0.f, 0.f}, a1c = {0.f, 0.f}, a2c = {0.f, 0.f}, a3c = {0.f, 0.f};

#define CFMA(acc, mr, mi, gr, gi)                 \
  acc.x = fmaf(mr, gr, acc.x);                    \
  acc.x = fmaf(-(mi), gi, acc.x);                 \
  acc.y = fmaf(mr, gi, acc.y);                    \
  acc.y = fmaf(mi, gr, acc.y)

  for (int b = 0; b < NN; b += 2) {
    float4 mm = Mrow[b >> 1];   // m[b]=(x,y)  m[b+1]=(z,w)
    CFMA(a0c, mm.x, mm.y, g1.z, g1.w);
    CFMA(a0c, mm.z, mm.w, g2.x, g2.y);
    CFMA(a1c, mm.x, mm.y, g1.x, g1.y);
    CFMA(a1c, mm.z, mm.w, g1.z, g1.w);
    CFMA(a2c, mm.x, mm.y, g0.z, g0.w);
    CFMA(a2c, mm.z, mm.w, g1.x, g1.y);
    CFMA(a3c, mm.x, mm.y, g0.x, g0.y);
    CFMA(a3c, mm.z, mm.w, g0.z, g0.w);
    g0 = g1;
    g1 = g2;
    g2 = Grow[gb + 3 + (b >> 1)];   // slack covers final overrun
  }
#undef CFMA

  int dbase = 4 * q;
  s_red[h * NN + dbase + 0] = a0c;
  s_red[h * NN + dbase + 1] = a1c;
  s_red[h * NN + dbase + 2] = a2c;
  s_red[h * NN + dbase + 3] = a3c;
  __syncthreads();

  if (t < NN) {
    float re = 0.f, im = 0.f;
    #pragma unroll
    for (int hh = 0; hh < 8; ++hh) {
      re += s_red[hh * NN + t].x;
      im += s_red[hh * NN + t].y;
    }
    int j = c * NN + t;
    if (interleaved) {
      atomicAdd(out + 2 * j,     re);
      atomicAdd(out + 2 * j + 1, im);
    } else {
      atomicAdd(out + j, re);
    }
  }
}

extern "C" void kernel_launch(void* const* d_in, const int* in_sizes, int n_in,
                              void* d_out, int out_size, void* d_ws, size_t ws_size,
                              hipStream_t stream) {
  const float* x  = (const float*)d_in[0];
  const float* w  = (const float*)d_in[1];
  const float* xc = (const float*)d_in[2];
  const float* yc = (const float*)d_in[3];
  float* out = (float*)d_out;

  int interleaved = (out_size >= 2 * M) ? 1 : 0;
  int out_floats  = interleaved ? 2 * M : M;

  int total = GH * GH + M;   // 45697 work items; out_floats < total covered
  precompute_kernel<<<(total + 255) / 256, 256, 0, stream>>>(
      x, w, xc, yc, out, out_floats);

  conv_kernel<<<dim3(NN, 12), 192, 0, stream>>>(out, interleaved);
}